// Round 1
// baseline (812.147 us; speedup 1.0000x reference)
//
#include <hip/hip_runtime.h>
#include <math.h>

#define B_SZ 2048
#define N_SZ 4096
#define D_SZ 512
#define INV_T 14.285714285714286f
#define KC 0.3989422804014327f

// ---------------- Kernel 1: rank table ----------------
// Rk[b][a] = #{ c in [0,B) : (l_b-l_c)^2 > (l_b-l_a)^2 }   (strictly-greater d^2
// == strictly-less Gaussian mask value, matching searchsorted 'left')
__global__ __launch_bounds__(256) void rank_kernel(const float* __restrict__ labels,
                                                   unsigned short* __restrict__ Rk) {
    __shared__ float rv[B_SZ];
    const int b = blockIdx.x;
    const int t = threadIdx.x;
    const float lb = labels[b];
#pragma unroll
    for (int s = 0; s < 8; ++s) {
        int c = t + 256 * s;
        float d = lb - labels[c];
        rv[c] = d * d;
    }
    __syncthreads();
    float va[8];
    int cnt[8];
#pragma unroll
    for (int s = 0; s < 8; ++s) { va[s] = rv[t + 256 * s]; cnt[s] = 0; }
    for (int c = 0; c < B_SZ; ++c) {
        float vc = rv[c];
#pragma unroll
        for (int s = 0; s < 8; ++s) cnt[s] += (vc > va[s]) ? 1 : 0;
    }
#pragma unroll
    for (int s = 0; s < 8; ++s)
        Rk[(size_t)b * B_SZ + t + 256 * s] = (unsigned short)cnt[s];
}

// ---------------- Kernel 2: fused GEMM + epilogue ----------------
// feats row i (view-major): v = i>>11, b = i&2047, base = (b*2+v)*512
__device__ __forceinline__ long long frow(int i) {
    return (long long)(((i & (B_SZ - 1)) << 1) | (i >> 11)) * D_SZ;
}

__global__ __launch_bounds__(256) void main_kernel(const float* __restrict__ feats,
                                                   const float* __restrict__ labels,
                                                   const unsigned short* __restrict__ Rk,
                                                   float* __restrict__ Uacc,
                                                   float* __restrict__ Wacc,
                                                   float* __restrict__ PSacc) {
    __shared__ float As[64 * 64];   // k-major: As[k][m]
    __shared__ float Bs[64 * 64];   // k-major: Bs[k][n]
    __shared__ float sli[64];
    __shared__ float slj[64];

    const int tx = threadIdx.x;     // 0..15
    const int ty = threadIdx.y;     // 0..15
    const int t = ty * 16 + tx;
    const int it64 = blockIdx.y * 64;       // i-tile base
    const int jc512 = blockIdx.x * 512;     // j-chunk base

    if (t < 64) sli[t] = labels[(it64 + t) & (B_SZ - 1)];

    float wsum[4] = {0.f, 0.f, 0.f, 0.f};
    float pssum[4] = {0.f, 0.f, 0.f, 0.f};
    float usum[4] = {0.f, 0.f, 0.f, 0.f};

    const int r = t >> 2;       // staged row 0..63
    const int c4 = t & 3;
    const long long abase = frow(it64 + r);

    for (int jt = 0; jt < 8; ++jt) {
        __syncthreads();   // previous epilogue finished reading slj
        const int jbase = jc512 + jt * 64;
        if (t < 64) slj[t] = labels[(jbase + t) & (B_SZ - 1)];

        float acc[4][4];
#pragma unroll
        for (int a = 0; a < 4; ++a)
#pragma unroll
            for (int b2 = 0; b2 < 4; ++b2) acc[a][b2] = 0.f;

        const long long bbase = frow(jbase + r);

        for (int kc = 0; kc < 8; ++kc) {
            const int k0 = kc * 64;
            __syncthreads();   // previous compute finished reading LDS
#pragma unroll
            for (int s = 0; s < 4; ++s) {
                int cq = c4 + 4 * s;   // float4 index within 64-col chunk
                float4 av = reinterpret_cast<const float4*>(feats + abase + k0)[cq];
                float4 bv = reinterpret_cast<const float4*>(feats + bbase + k0)[cq];
                int kk = cq * 4;
                As[(kk + 0) * 64 + r] = av.x;
                As[(kk + 1) * 64 + r] = av.y;
                As[(kk + 2) * 64 + r] = av.z;
                As[(kk + 3) * 64 + r] = av.w;
                Bs[(kk + 0) * 64 + r] = bv.x;
                Bs[(kk + 1) * 64 + r] = bv.y;
                Bs[(kk + 2) * 64 + r] = bv.z;
                Bs[(kk + 3) * 64 + r] = bv.w;
            }
            __syncthreads();
#pragma unroll 8
            for (int k = 0; k < 64; ++k) {
                float4 av = *reinterpret_cast<const float4*>(&As[k * 64 + ty * 4]);
                float4 bv = *reinterpret_cast<const float4*>(&Bs[k * 64 + tx * 4]);
                float aarr[4] = {av.x, av.y, av.z, av.w};
                float barr[4] = {bv.x, bv.y, bv.z, bv.w};
#pragma unroll
                for (int mi = 0; mi < 4; ++mi)
#pragma unroll
                    for (int nj = 0; nj < 4; ++nj)
                        acc[mi][nj] = fmaf(aarr[mi], barr[nj], acc[mi][nj]);
            }
        }

        // epilogue for this 64x64 S-tile
        const int ib0 = (it64 + ty * 4) & (B_SZ - 1);
#pragma unroll
        for (int nj = 0; nj < 4; ++nj) {
            const int j_g = jbase + tx * 4 + nj;
            const int jb = j_g & (B_SZ - 1);
            const float ljv = slj[tx * 4 + nj];
            ushort4 rk4 = *reinterpret_cast<const ushort4*>(Rk + (size_t)jb * B_SZ + ib0);
            unsigned short rr[4] = {rk4.x, rk4.y, rk4.z, rk4.w};
#pragma unroll
            for (int mi = 0; mi < 4; ++mi) {
                const int i_g = it64 + ty * 4 + mi;
                const float s = acc[mi][nj] * INV_T;
                if (i_g != j_g) {
                    float dl = sli[ty * 4 + mi] - ljv;
                    float msk = expf(dl * dl * (-0.5f)) * KC;
                    wsum[mi] += msk;
                    pssum[mi] = fmaf(msk, s, pssum[mi]);
                    usum[mi] = fmaf(expf(s - INV_T), 2.0f * (float)rr[mi], usum[mi]);
                }
            }
        }
    }

    // reduce across the 16 tx-lanes of each ty-group, then one atomic per row
#pragma unroll
    for (int mi = 0; mi < 4; ++mi) {
        float w = wsum[mi], ps = pssum[mi], u = usum[mi];
#pragma unroll
        for (int off = 8; off >= 1; off >>= 1) {
            w += __shfl_xor(w, off, 16);
            ps += __shfl_xor(ps, off, 16);
            u += __shfl_xor(u, off, 16);
        }
        if (tx == 0) {
            const int row = it64 + ty * 4 + mi;
            atomicAdd(&Wacc[row], w);
            atomicAdd(&PSacc[row], ps);
            atomicAdd(&Uacc[row], u);
        }
    }
}

// ---------------- Kernel 3: final reduce ----------------
__global__ __launch_bounds__(256) void finish_kernel(const float* __restrict__ Uacc,
                                                     const float* __restrict__ Wacc,
                                                     const float* __restrict__ PSacc,
                                                     float* __restrict__ out) {
    __shared__ float red[4];
    const int t = threadIdx.x;
    float sum = 0.f;
    for (int r2 = t; r2 < N_SZ; r2 += 256)
        sum += PSacc[r2] / Wacc[r2] - INV_T - logf(Uacc[r2]);
#pragma unroll
    for (int off = 32; off >= 1; off >>= 1) sum += __shfl_xor(sum, off, 64);
    if ((t & 63) == 0) red[t >> 6] = sum;
    __syncthreads();
    if (t == 0) {
        float tot = red[0] + red[1] + red[2] + red[3];
        out[0] = -tot / (float)N_SZ;
    }
}

extern "C" void kernel_launch(void* const* d_in, const int* in_sizes, int n_in,
                              void* d_out, int out_size, void* d_ws, size_t ws_size,
                              hipStream_t stream) {
    const float* feats = (const float*)d_in[0];
    const float* labels = (const float*)d_in[1];
    float* out = (float*)d_out;

    char* ws = (char*)d_ws;
    unsigned short* Rk = (unsigned short*)ws;
    const size_t rk_bytes = (size_t)B_SZ * B_SZ * sizeof(unsigned short);  // 8 MB
    float* Uacc = (float*)(ws + rk_bytes);
    float* Wacc = Uacc + N_SZ;
    float* PSacc = Wacc + N_SZ;

    hipMemsetAsync(Uacc, 0, 3 * N_SZ * sizeof(float), stream);
    rank_kernel<<<dim3(B_SZ), dim3(256), 0, stream>>>(labels, Rk);
    main_kernel<<<dim3(8, 64), dim3(16, 16), 0, stream>>>(feats, labels, Rk, Uacc, Wacc, PSacc);
    finish_kernel<<<dim3(1), dim3(256), 0, stream>>>(Uacc, Wacc, PSacc, out);
}

// Round 2
// 437.333 us; speedup vs baseline: 1.8570x; 1.8570x over previous
//
#include <hip/hip_runtime.h>
#include <math.h>

#define B_SZ 2048
#define N_SZ 4096
#define D_SZ 512
#define INV_T 14.285714285714286f
#define KC 0.3989422804014327f

// ---------------- Kernel 0: global counting-sort of labels ----------------
// sorted[rank(a)] = labels[a], rank = #{c: l_c < l_a || (l_c==l_a && c<a)}
__global__ __launch_bounds__(256) void sort_kernel(const float* __restrict__ labels,
                                                   float* __restrict__ sorted) {
    __shared__ float lv[B_SZ];
    const int t = threadIdx.x;
#pragma unroll
    for (int s = 0; s < 8; ++s) lv[t + 256 * s] = labels[t + 256 * s];
    __syncthreads();
    const int a = blockIdx.x * 256 + t;
    const float la = lv[a];
    int cnt = 0;
    for (int c = 0; c < B_SZ; ++c) {
        float lc = lv[c];
        cnt += (lc < la || (lc == la && c < a)) ? 1 : 0;
    }
    sorted[cnt] = la;
}

// ---------------- Kernel 1: rank table via binary search ----------------
// Rk[b][a] = B - #{c : |l_b - l_c| <= |l_b - l_a|}
// d(q) = l_b - sorted[q] is monotone non-increasing in q, so the <=t set is a
// contiguous interval [p1, p2): p1 = #{q: d(q) > t}, p2 = #{q: d(q) >= -t}.
__global__ __launch_bounds__(256) void rank_kernel(const float* __restrict__ labels,
                                                   const float* __restrict__ sorted,
                                                   unsigned short* __restrict__ Rk) {
    __shared__ float Ls[B_SZ];
    const int b = blockIdx.x;
    const int t = threadIdx.x;
#pragma unroll
    for (int s = 0; s < 8; ++s) Ls[t + 256 * s] = sorted[t + 256 * s];
    const float lb = labels[b];
    float tv[8];
    int p1[8], p2[8];
#pragma unroll
    for (int s = 0; s < 8; ++s) {
        float d = lb - labels[t + 256 * s];
        tv[s] = fabsf(d);
        p1[s] = 0;
        p2[s] = 0;
    }
    __syncthreads();
#pragma unroll
    for (int step = 2048; step; step >>= 1) {
#pragma unroll
        for (int s = 0; s < 8; ++s) {
            unsigned q1 = (unsigned)(p1[s] + step - 1);
            float d1 = lb - Ls[q1 & (B_SZ - 1)];
            if (q1 < B_SZ && d1 > tv[s]) p1[s] += step;
            unsigned q2 = (unsigned)(p2[s] + step - 1);
            float d2 = lb - Ls[q2 & (B_SZ - 1)];
            if (q2 < B_SZ && d2 >= -tv[s]) p2[s] += step;
        }
    }
#pragma unroll
    for (int s = 0; s < 8; ++s)
        Rk[(size_t)b * B_SZ + t + 256 * s] = (unsigned short)(B_SZ - (p2[s] - p1[s]));
}

// ---------------- Kernel 2: fused GEMM + epilogue ----------------
// feats row i (view-major): v = i>>11, b = i&2047, base = (b*2+v)*512
__device__ __forceinline__ long long frow(int i) {
    return (long long)(((i & (B_SZ - 1)) << 1) | (i >> 11)) * D_SZ;
}

__global__ __launch_bounds__(256) void main_kernel(const float* __restrict__ feats,
                                                   const float* __restrict__ labels,
                                                   const unsigned short* __restrict__ Rk,
                                                   float* __restrict__ Uacc,
                                                   float* __restrict__ Wacc,
                                                   float* __restrict__ PSacc) {
    __shared__ float As[64 * 64];   // k-major: As[k][m]
    __shared__ float Bs[64 * 64];   // k-major: Bs[k][n]
    __shared__ float sli[64];
    __shared__ float slj[64];

    const int tx = threadIdx.x;     // 0..15
    const int ty = threadIdx.y;     // 0..15
    const int t = ty * 16 + tx;
    const int it64 = blockIdx.y * 64;       // i-tile base
    const int jc512 = blockIdx.x * 512;     // j-chunk base

    if (t < 64) sli[t] = labels[(it64 + t) & (B_SZ - 1)];

    float wsum[4] = {0.f, 0.f, 0.f, 0.f};
    float pssum[4] = {0.f, 0.f, 0.f, 0.f};
    float usum[4] = {0.f, 0.f, 0.f, 0.f};

    const int r = t >> 2;       // staged row 0..63
    const int c4 = t & 3;
    const long long abase = frow(it64 + r);

    for (int jt = 0; jt < 8; ++jt) {
        __syncthreads();   // previous epilogue finished reading slj
        const int jbase = jc512 + jt * 64;
        if (t < 64) slj[t] = labels[(jbase + t) & (B_SZ - 1)];

        float acc[4][4];
#pragma unroll
        for (int a = 0; a < 4; ++a)
#pragma unroll
            for (int b2 = 0; b2 < 4; ++b2) acc[a][b2] = 0.f;

        const long long bbase = frow(jbase + r);

        for (int kc = 0; kc < 8; ++kc) {
            const int k0 = kc * 64;
            __syncthreads();   // previous compute finished reading LDS
#pragma unroll
            for (int s = 0; s < 4; ++s) {
                int cq = c4 + 4 * s;   // float4 index within 64-col chunk
                float4 av = reinterpret_cast<const float4*>(feats + abase + k0)[cq];
                float4 bv = reinterpret_cast<const float4*>(feats + bbase + k0)[cq];
                int kk = cq * 4;
                As[(kk + 0) * 64 + r] = av.x;
                As[(kk + 1) * 64 + r] = av.y;
                As[(kk + 2) * 64 + r] = av.z;
                As[(kk + 3) * 64 + r] = av.w;
                Bs[(kk + 0) * 64 + r] = bv.x;
                Bs[(kk + 1) * 64 + r] = bv.y;
                Bs[(kk + 2) * 64 + r] = bv.z;
                Bs[(kk + 3) * 64 + r] = bv.w;
            }
            __syncthreads();
#pragma unroll 8
            for (int k = 0; k < 64; ++k) {
                float4 av = *reinterpret_cast<const float4*>(&As[k * 64 + ty * 4]);
                float4 bv = *reinterpret_cast<const float4*>(&Bs[k * 64 + tx * 4]);
                float aarr[4] = {av.x, av.y, av.z, av.w};
                float barr[4] = {bv.x, bv.y, bv.z, bv.w};
#pragma unroll
                for (int mi = 0; mi < 4; ++mi)
#pragma unroll
                    for (int nj = 0; nj < 4; ++nj)
                        acc[mi][nj] = fmaf(aarr[mi], barr[nj], acc[mi][nj]);
            }
        }

        // epilogue for this 64x64 S-tile
        const int ib0 = (it64 + ty * 4) & (B_SZ - 1);
#pragma unroll
        for (int nj = 0; nj < 4; ++nj) {
            const int j_g = jbase + tx * 4 + nj;
            const int jb = j_g & (B_SZ - 1);
            const float ljv = slj[tx * 4 + nj];
            ushort4 rk4 = *reinterpret_cast<const ushort4*>(Rk + (size_t)jb * B_SZ + ib0);
            unsigned short rr[4] = {rk4.x, rk4.y, rk4.z, rk4.w};
#pragma unroll
            for (int mi = 0; mi < 4; ++mi) {
                const int i_g = it64 + ty * 4 + mi;
                const float s = acc[mi][nj] * INV_T;
                if (i_g != j_g) {
                    float dl = sli[ty * 4 + mi] - ljv;
                    float msk = expf(dl * dl * (-0.5f)) * KC;
                    wsum[mi] += msk;
                    pssum[mi] = fmaf(msk, s, pssum[mi]);
                    usum[mi] = fmaf(expf(s - INV_T), 2.0f * (float)rr[mi], usum[mi]);
                }
            }
        }
    }

    // reduce across the 16 tx-lanes of each ty-group, then one atomic per row
#pragma unroll
    for (int mi = 0; mi < 4; ++mi) {
        float w = wsum[mi], ps = pssum[mi], u = usum[mi];
#pragma unroll
        for (int off = 8; off >= 1; off >>= 1) {
            w += __shfl_xor(w, off, 16);
            ps += __shfl_xor(ps, off, 16);
            u += __shfl_xor(u, off, 16);
        }
        if (tx == 0) {
            const int row = it64 + ty * 4 + mi;
            atomicAdd(&Wacc[row], w);
            atomicAdd(&PSacc[row], ps);
            atomicAdd(&Uacc[row], u);
        }
    }
}

// ---------------- Kernel 3: final reduce ----------------
__global__ __launch_bounds__(256) void finish_kernel(const float* __restrict__ Uacc,
                                                     const float* __restrict__ Wacc,
                                                     const float* __restrict__ PSacc,
                                                     float* __restrict__ out) {
    __shared__ float red[4];
    const int t = threadIdx.x;
    float sum = 0.f;
    for (int r2 = t; r2 < N_SZ; r2 += 256)
        sum += PSacc[r2] / Wacc[r2] - INV_T - logf(Uacc[r2]);
#pragma unroll
    for (int off = 32; off >= 1; off >>= 1) sum += __shfl_xor(sum, off, 64);
    if ((t & 63) == 0) red[t >> 6] = sum;
    __syncthreads();
    if (t == 0) {
        float tot = red[0] + red[1] + red[2] + red[3];
        out[0] = -tot / (float)N_SZ;
    }
}

extern "C" void kernel_launch(void* const* d_in, const int* in_sizes, int n_in,
                              void* d_out, int out_size, void* d_ws, size_t ws_size,
                              hipStream_t stream) {
    const float* feats = (const float*)d_in[0];
    const float* labels = (const float*)d_in[1];
    float* out = (float*)d_out;

    char* ws = (char*)d_ws;
    unsigned short* Rk = (unsigned short*)ws;
    const size_t rk_bytes = (size_t)B_SZ * B_SZ * sizeof(unsigned short);  // 8 MB
    float* Uacc = (float*)(ws + rk_bytes);
    float* Wacc = Uacc + N_SZ;
    float* PSacc = Wacc + N_SZ;
    float* sorted = PSacc + N_SZ;

    hipMemsetAsync(Uacc, 0, 3 * N_SZ * sizeof(float), stream);
    sort_kernel<<<dim3(8), dim3(256), 0, stream>>>(labels, sorted);
    rank_kernel<<<dim3(B_SZ), dim3(256), 0, stream>>>(labels, sorted, Rk);
    main_kernel<<<dim3(8, 64), dim3(16, 16), 0, stream>>>(feats, labels, Rk, Uacc, Wacc, PSacc);
    finish_kernel<<<dim3(1), dim3(256), 0, stream>>>(Uacc, Wacc, PSacc, out);
}

// Round 3
// 247.993 us; speedup vs baseline: 3.2749x; 1.7635x over previous
//
#include <hip/hip_runtime.h>
#include <math.h>

#define B_SZ 2048
#define N_SZ 4096
#define D_SZ 512
#define INV_T 14.285714285714286f
#define KC 0.3989422804014327f
#define BK 32

typedef __bf16 bf16x8 __attribute__((ext_vector_type(8)));
typedef __bf16 bf16x2 __attribute__((ext_vector_type(2)));
typedef float f32x4 __attribute__((ext_vector_type(4)));

// feats row i (view-major concat): v = i>>11, b = i&2047, src row = b*2+v
__device__ __forceinline__ long long frow(int i) {
    return (long long)(((i & (B_SZ - 1)) << 1) | (i >> 11)) * D_SZ;
}

// ---------------- Kernel A: fp32 -> (hi, lo) bf16 split, permuted row order ----
__global__ __launch_bounds__(256) void conv_kernel(const float* __restrict__ feats,
                                                   __bf16* __restrict__ Hp,
                                                   __bf16* __restrict__ Lp) {
    const int r = blockIdx.x;
    const int t = threadIdx.x;
    const float2 v = *reinterpret_cast<const float2*>(&feats[frow(r) + 2 * t]);
    __bf16 h0 = (__bf16)v.x;
    __bf16 h1 = (__bf16)v.y;
    __bf16 l0 = (__bf16)(v.x - (float)h0);
    __bf16 l1 = (__bf16)(v.y - (float)h1);
    bf16x2 hh = {h0, h1};
    bf16x2 ll = {l0, l1};
    *reinterpret_cast<bf16x2*>(&Hp[(size_t)r * D_SZ + 2 * t]) = hh;
    *reinterpret_cast<bf16x2*>(&Lp[(size_t)r * D_SZ + 2 * t]) = ll;
}

// ---------------- Kernel 0: global counting-sort of labels ----------------
__global__ __launch_bounds__(256) void sort_kernel(const float* __restrict__ labels,
                                                   float* __restrict__ sorted) {
    __shared__ float lv[B_SZ];
    const int t = threadIdx.x;
#pragma unroll
    for (int s = 0; s < 8; ++s) lv[t + 256 * s] = labels[t + 256 * s];
    __syncthreads();
    const int a = blockIdx.x * 256 + t;
    const float la = lv[a];
    int cnt = 0;
    for (int c = 0; c < B_SZ; ++c) {
        float lc = lv[c];
        cnt += (lc < la || (lc == la && c < a)) ? 1 : 0;
    }
    sorted[cnt] = la;
}

// ---------------- Kernel 1: rank table via binary search ----------------
__global__ __launch_bounds__(256) void rank_kernel(const float* __restrict__ labels,
                                                   const float* __restrict__ sorted,
                                                   unsigned short* __restrict__ Rk) {
    __shared__ float Ls[B_SZ];
    const int b = blockIdx.x;
    const int t = threadIdx.x;
#pragma unroll
    for (int s = 0; s < 8; ++s) Ls[t + 256 * s] = sorted[t + 256 * s];
    const float lb = labels[b];
    float tv[8];
    int p1[8], p2[8];
#pragma unroll
    for (int s = 0; s < 8; ++s) {
        float d = lb - labels[t + 256 * s];
        tv[s] = fabsf(d);
        p1[s] = 0;
        p2[s] = 0;
    }
    __syncthreads();
#pragma unroll
    for (int step = 2048; step; step >>= 1) {
#pragma unroll
        for (int s = 0; s < 8; ++s) {
            unsigned q1 = (unsigned)(p1[s] + step - 1);
            float d1 = lb - Ls[q1 & (B_SZ - 1)];
            if (q1 < B_SZ && d1 > tv[s]) p1[s] += step;
            unsigned q2 = (unsigned)(p2[s] + step - 1);
            float d2 = lb - Ls[q2 & (B_SZ - 1)];
            if (q2 < B_SZ && d2 >= -tv[s]) p2[s] += step;
        }
    }
#pragma unroll
    for (int s = 0; s < 8; ++s)
        Rk[(size_t)b * B_SZ + t + 256 * s] = (unsigned short)(B_SZ - (p2[s] - p1[s]));
}

// ---------------- Kernel 2: MFMA bf16x3 GEMM + fused epilogue ----------------
// 128x128 tile/block, 4 waves each 64x64 (4x4 of 16x16x32 mfma).
// S = H*H^T + H*L^T + L*H^T (drops L*L^T ~4e-6).
__global__ __launch_bounds__(256) void main_kernel(const __bf16* __restrict__ Hp,
                                                   const __bf16* __restrict__ Lp,
                                                   const float* __restrict__ labels,
                                                   const unsigned short* __restrict__ Rk,
                                                   float* __restrict__ Uacc,
                                                   float* __restrict__ Wacc,
                                                   float* __restrict__ PSacc) {
    __shared__ __bf16 S[4][128 * BK];   // Ah, Al, Bh, Bl : 8 KB each
    __shared__ float sli[128], slj[128];

    const int t = threadIdx.x;
    const int w = t >> 6;           // wave 0..3
    const int l = t & 63;
    const int it = blockIdx.y * 128;
    const int jt = blockIdx.x * 128;

    if (t < 128) sli[t] = labels[(it + t) & (B_SZ - 1)];
    else slj[t - 128] = labels[(jt + t - 128) & (B_SZ - 1)];

    // --- staging setup: wave w fills tile w (0:Ah 1:Al 2:Bh 3:Bl) ---
    const __bf16* src = (w & 1) ? Lp : Hp;
    const int tb = (w < 2) ? it : jt;
    const int lrow = l >> 2;                        // row within 16-row group
    const int gblk = (l & 3) ^ ((l >> 3) & 3);      // XOR-swizzled 16B block
    const __bf16* gbase = src + (size_t)(tb + lrow) * D_SZ + gblk * 8;
    __bf16* myTile = S[w];

    // --- fragment setup (verified m91 mapping, NT GEMM) ---
    const int lr = l & 15;
    const int quad = l >> 4;
    const int swz = (lr >> 1) & 3;                  // row swizzle, lane-constant
    const int wy = w >> 1, wx = w & 1;
    const int aoff = (wy * 64 + lr) * BK + ((quad ^ swz) * 8);
    const int boff = (wx * 64 + lr) * BK + ((quad ^ swz) * 8);

    f32x4 acc[4][4];
#pragma unroll
    for (int mi = 0; mi < 4; ++mi)
#pragma unroll
        for (int nj = 0; nj < 4; ++nj) acc[mi][nj] = {0.f, 0.f, 0.f, 0.f};

    for (int kt = 0; kt < D_SZ / BK; ++kt) {
        __syncthreads();   // previous iter's frag reads done (iter0: labels written)
        const __bf16* g = gbase + kt * BK;
#pragma unroll
        for (int q = 0; q < 8; ++q) {
            __builtin_amdgcn_global_load_lds(
                (const __attribute__((address_space(1))) void*)(g + (size_t)q * 16 * D_SZ),
                (__attribute__((address_space(3))) void*)(myTile + q * 16 * BK + l * 8),
                16, 0, 0);
        }
        __syncthreads();   // vmcnt drained by compiler before barrier

        bf16x8 bh[4], bl[4];
#pragma unroll
        for (int nj = 0; nj < 4; ++nj) {
            bh[nj] = *reinterpret_cast<const bf16x8*>(&S[2][boff + nj * 16 * BK]);
            bl[nj] = *reinterpret_cast<const bf16x8*>(&S[3][boff + nj * 16 * BK]);
        }
#pragma unroll
        for (int mi = 0; mi < 4; ++mi) {
            bf16x8 ah = *reinterpret_cast<const bf16x8*>(&S[0][aoff + mi * 16 * BK]);
            bf16x8 al = *reinterpret_cast<const bf16x8*>(&S[1][aoff + mi * 16 * BK]);
#pragma unroll
            for (int nj = 0; nj < 4; ++nj) {
                acc[mi][nj] = __builtin_amdgcn_mfma_f32_16x16x32_bf16(ah, bh[nj], acc[mi][nj], 0, 0, 0);
                acc[mi][nj] = __builtin_amdgcn_mfma_f32_16x16x32_bf16(ah, bl[nj], acc[mi][nj], 0, 0, 0);
                acc[mi][nj] = __builtin_amdgcn_mfma_f32_16x16x32_bf16(al, bh[nj], acc[mi][nj], 0, 0, 0);
            }
        }
    }

    // --- fused epilogue: D[row=quad*4+reg][col=lr] ---
    float rw[16], rp[16], ru[16];
#pragma unroll
    for (int x = 0; x < 16; ++x) { rw[x] = 0.f; rp[x] = 0.f; ru[x] = 0.f; }

    const int jcol = wx * 64 + lr;
    const int irow0 = wy * 64 + quad * 4;
#pragma unroll
    for (int nj = 0; nj < 4; ++nj) {
        const int j_g = jt + jcol + nj * 16;
        const int jb = j_g & (B_SZ - 1);
        const float lj = slj[jcol + nj * 16];
        const unsigned short* rkrow = Rk + (size_t)jb * B_SZ;
#pragma unroll
        for (int mi = 0; mi < 4; ++mi) {
            const int i0 = it + irow0 + mi * 16;
            ushort4 rk4 = *reinterpret_cast<const ushort4*>(&rkrow[i0 & (B_SZ - 1)]);
            const unsigned short rr[4] = {rk4.x, rk4.y, rk4.z, rk4.w};
#pragma unroll
            for (int reg = 0; reg < 4; ++reg) {
                const int i_g = i0 + reg;
                if (i_g != j_g) {
                    const float s = acc[mi][nj][reg] * INV_T;
                    const float dl = sli[irow0 + mi * 16 + reg] - lj;
                    const float msk = __expf(dl * dl * (-0.5f)) * KC;
                    const int x = mi * 4 + reg;
                    rw[x] += msk;
                    rp[x] = fmaf(msk, s, rp[x]);
                    ru[x] = fmaf(__expf(s - INV_T), 2.0f * (float)rr[reg], ru[x]);
                }
            }
        }
    }

    // reduce across the 16 lanes sharing each row, one atomic per row
#pragma unroll
    for (int mi = 0; mi < 4; ++mi) {
#pragma unroll
        for (int reg = 0; reg < 4; ++reg) {
            const int x = mi * 4 + reg;
            float a = rw[x], b = rp[x], c = ru[x];
#pragma unroll
            for (int off = 8; off >= 1; off >>= 1) {
                a += __shfl_xor(a, off, 16);
                b += __shfl_xor(b, off, 16);
                c += __shfl_xor(c, off, 16);
            }
            if (lr == 0) {
                const int row = it + irow0 + mi * 16 + reg;
                atomicAdd(&Wacc[row], a);
                atomicAdd(&PSacc[row], b);
                atomicAdd(&Uacc[row], c);
            }
        }
    }
}

// ---------------- Kernel 3: final reduce ----------------
__global__ __launch_bounds__(256) void finish_kernel(const float* __restrict__ Uacc,
                                                     const float* __restrict__ Wacc,
                                                     const float* __restrict__ PSacc,
                                                     float* __restrict__ out) {
    __shared__ float red[4];
    const int t = threadIdx.x;
    float sum = 0.f;
    for (int r2 = t; r2 < N_SZ; r2 += 256)
        sum += PSacc[r2] / Wacc[r2] - INV_T - logf(Uacc[r2]);
#pragma unroll
    for (int off = 32; off >= 1; off >>= 1) sum += __shfl_xor(sum, off, 64);
    if ((t & 63) == 0) red[t >> 6] = sum;
    __syncthreads();
    if (t == 0) {
        float tot = red[0] + red[1] + red[2] + red[3];
        out[0] = -tot / (float)N_SZ;
    }
}

extern "C" void kernel_launch(void* const* d_in, const int* in_sizes, int n_in,
                              void* d_out, int out_size, void* d_ws, size_t ws_size,
                              hipStream_t stream) {
    const float* feats = (const float*)d_in[0];
    const float* labels = (const float*)d_in[1];
    float* out = (float*)d_out;

    char* ws = (char*)d_ws;
    unsigned short* Rk = (unsigned short*)ws;
    const size_t rk_bytes = (size_t)B_SZ * B_SZ * sizeof(unsigned short);  // 8 MB
    float* Uacc = (float*)(ws + rk_bytes);
    float* Wacc = Uacc + N_SZ;
    float* PSacc = Wacc + N_SZ;
    float* sorted = PSacc + N_SZ;
    __bf16* Hp = (__bf16*)(sorted + B_SZ);
    __bf16* Lp = Hp + (size_t)N_SZ * D_SZ;

    hipMemsetAsync(Uacc, 0, 3 * N_SZ * sizeof(float), stream);
    conv_kernel<<<dim3(N_SZ), dim3(256), 0, stream>>>(feats, Hp, Lp);
    sort_kernel<<<dim3(8), dim3(256), 0, stream>>>(labels, sorted);
    rank_kernel<<<dim3(B_SZ), dim3(256), 0, stream>>>(labels, sorted, Rk);
    main_kernel<<<dim3(32, 32), dim3(256), 0, stream>>>(Hp, Lp, labels, Rk, Uacc, Wacc, PSacc);
    finish_kernel<<<dim3(1), dim3(256), 0, stream>>>(Uacc, Wacc, PSacc, out);
}

// Round 4
// 222.286 us; speedup vs baseline: 3.6536x; 1.1156x over previous
//
#include <hip/hip_runtime.h>
#include <math.h>

#define B_SZ 2048
#define N_SZ 4096
#define D_SZ 512
#define INV_T 14.285714285714286f
#define KC 0.3989422804014327f
#define BK 32

typedef __bf16 bf16x8 __attribute__((ext_vector_type(8)));
typedef __bf16 bf16x2 __attribute__((ext_vector_type(2)));
typedef float f32x4 __attribute__((ext_vector_type(4)));

// feats row i (view-major concat): v = i>>11, b = i&2047, src row = b*2+v
__device__ __forceinline__ long long frow(int i) {
    return (long long)(((i & (B_SZ - 1)) << 1) | (i >> 11)) * D_SZ;
}

// ---------------- Kernel A: fp32 -> bf16 (RNE), permuted row order ----------
__global__ __launch_bounds__(256) void conv_kernel(const float* __restrict__ feats,
                                                   __bf16* __restrict__ Hp) {
    const int r = blockIdx.x;
    const int t = threadIdx.x;
    const float2 v = *reinterpret_cast<const float2*>(&feats[frow(r) + 2 * t]);
    bf16x2 hh = {(__bf16)v.x, (__bf16)v.y};
    *reinterpret_cast<bf16x2*>(&Hp[(size_t)r * D_SZ + 2 * t]) = hh;
}

// ---------------- Kernel 0: counting-sort + per-label global ranks ----------
// sorted[rank(a)] = l_a;  lo[a] = #{c: l_c < l_a};  hi[a] = #{c: l_c <= l_a}
__global__ __launch_bounds__(256) void sort_kernel(const float* __restrict__ labels,
                                                   float* __restrict__ sorted,
                                                   unsigned short* __restrict__ lo,
                                                   unsigned short* __restrict__ hi) {
    __shared__ float lv[B_SZ];
    const int t = threadIdx.x;
#pragma unroll
    for (int s = 0; s < 8; ++s) lv[t + 256 * s] = labels[t + 256 * s];
    const int a = blockIdx.x * 256 + t;
    const float la = labels[a];
    __syncthreads();
    int lt = 0, le = 0, tlo = 0;
    for (int c4 = 0; c4 < B_SZ / 4; ++c4) {
        float4 v = reinterpret_cast<const float4*>(lv)[c4];
        const float vv[4] = {v.x, v.y, v.z, v.w};
#pragma unroll
        for (int e = 0; e < 4; ++e) {
            lt += (vv[e] < la) ? 1 : 0;
            le += (vv[e] <= la) ? 1 : 0;
            tlo += (vv[e] == la && (4 * c4 + e) < a) ? 1 : 0;
        }
    }
    sorted[lt + tlo] = la;
    lo[a] = (unsigned short)lt;
    hi[a] = (unsigned short)le;
}

// ---------------- Kernel 1: rank table, ONE binary search per entry ---------
// Rk[b][a] = B - #{c: |l_b-l_c| <= |l_b-l_a|}.  The <=t set is the interval
// [l_b-t, l_b+t]; the near end (~l_a) count is precomputed (lo/hi), only the
// far end is searched:  la<=lb: inner = ub(lb+t) - lo[a]
//                       la> lb: inner = hi[a] - lb(lb-t)
__global__ __launch_bounds__(256) void rank_kernel(const float* __restrict__ labels,
                                                   const float* __restrict__ sorted,
                                                   const unsigned short* __restrict__ lo,
                                                   const unsigned short* __restrict__ hi,
                                                   unsigned short* __restrict__ Rk) {
    __shared__ float Ls[B_SZ];
    const int b = blockIdx.x;
    const int t = threadIdx.x;
#pragma unroll
    for (int s = 0; s < 8; ++s) Ls[t + 256 * s] = sorted[t + 256 * s];
    const float lb = labels[b];
    float x[8];
    int p[8], nearc[8];
    bool inc[8];
#pragma unroll
    for (int s = 0; s < 8; ++s) {
        const int a = t + 256 * s;
        const float la = labels[a];
        const float ts = fabsf(lb - la);
        inc[s] = (la <= lb);
        x[s] = inc[s] ? (lb + ts) : (lb - ts);
        nearc[s] = inc[s] ? (int)lo[a] : (int)hi[a];
        p[s] = 0;
    }
    __syncthreads();
#pragma unroll
    for (int step = B_SZ; step; step >>= 1) {
#pragma unroll
        for (int s = 0; s < 8; ++s) {
            const unsigned q = (unsigned)(p[s] + step - 1);
            const float Lq = Ls[q & (B_SZ - 1)];
            const bool cond = (Lq < x[s]) || (Lq == x[s] && inc[s]);
            if (q < B_SZ && cond) p[s] += step;
        }
    }
#pragma unroll
    for (int s = 0; s < 8; ++s) {
        const int inner = inc[s] ? (p[s] - nearc[s]) : (nearc[s] - p[s]);
        Rk[(size_t)b * B_SZ + t + 256 * s] = (unsigned short)(B_SZ - inner);
    }
}

// ---------------- Kernel 2: MFMA bf16 GEMM + fused epilogue -----------------
// 128x128 tile/block, 4 waves each 64x64 (4x4 of 16x16x32 mfma), S ~= H*H^T.
__global__ __launch_bounds__(256) void main_kernel(const __bf16* __restrict__ Hp,
                                                   const float* __restrict__ labels,
                                                   const unsigned short* __restrict__ Rk,
                                                   float* __restrict__ Uacc,
                                                   float* __restrict__ Wacc,
                                                   float* __restrict__ PSacc) {
    __shared__ __bf16 S[2][128 * BK];   // A, B : 8 KB each
    __shared__ float sli[128], slj[128];

    const int t = threadIdx.x;
    const int w = t >> 6;           // wave 0..3
    const int l = t & 63;
    const int it = blockIdx.y * 128;
    const int jt = blockIdx.x * 128;

    if (t < 128) sli[t] = labels[(it + t) & (B_SZ - 1)];
    else slj[t - 128] = labels[(jt + t - 128) & (B_SZ - 1)];

    // --- staging: wave w fills half (w&1) of tile (w>>1); 0=A(i) 1=B(j) ---
    const int tileidx = w >> 1;
    const int half = w & 1;
    const int tb = tileidx ? jt : it;
    const int gblk = (l & 3) ^ ((l >> 3) & 3);      // XOR-swizzled 16B block
    const __bf16* gbase = Hp + (size_t)(tb + half * 64 + (l >> 2)) * D_SZ + gblk * 8;
    __bf16* myTile = S[tileidx] + (half * 64) * BK;

    // --- fragment mapping (verified m91, NT GEMM) ---
    const int lr = l & 15;
    const int quad = l >> 4;
    const int swz = (lr >> 1) & 3;
    const int wy = w >> 1, wx = w & 1;
    const int aoff = (wy * 64 + lr) * BK + ((quad ^ swz) * 8);
    const int boff = (wx * 64 + lr) * BK + ((quad ^ swz) * 8);

    f32x4 acc[4][4];
#pragma unroll
    for (int mi = 0; mi < 4; ++mi)
#pragma unroll
        for (int nj = 0; nj < 4; ++nj) acc[mi][nj] = {0.f, 0.f, 0.f, 0.f};

    for (int kt = 0; kt < D_SZ / BK; ++kt) {
        __syncthreads();   // prior frag reads done (iter0: labels written)
        const __bf16* g = gbase + kt * BK;
#pragma unroll
        for (int q = 0; q < 4; ++q) {
            __builtin_amdgcn_global_load_lds(
                (const __attribute__((address_space(1))) void*)(g + (size_t)q * 16 * D_SZ),
                (__attribute__((address_space(3))) void*)(myTile + q * 16 * BK + l * 8),
                16, 0, 0);
        }
        __syncthreads();

        bf16x8 bh[4];
#pragma unroll
        for (int nj = 0; nj < 4; ++nj)
            bh[nj] = *reinterpret_cast<const bf16x8*>(&S[1][boff + nj * 16 * BK]);
#pragma unroll
        for (int mi = 0; mi < 4; ++mi) {
            bf16x8 ah = *reinterpret_cast<const bf16x8*>(&S[0][aoff + mi * 16 * BK]);
#pragma unroll
            for (int nj = 0; nj < 4; ++nj)
                acc[mi][nj] = __builtin_amdgcn_mfma_f32_16x16x32_bf16(ah, bh[nj], acc[mi][nj], 0, 0, 0);
        }
    }

    // --- fused epilogue: D[row=quad*4+reg][col=lr] ---
    float rw[16], rp[16], ru[16];
#pragma unroll
    for (int x = 0; x < 16; ++x) { rw[x] = 0.f; rp[x] = 0.f; ru[x] = 0.f; }

    const int jcol = wx * 64 + lr;
    const int irow0 = wy * 64 + quad * 4;
#pragma unroll
    for (int nj = 0; nj < 4; ++nj) {
        const int j_g = jt + jcol + nj * 16;
        const int jb = j_g & (B_SZ - 1);
        const float lj = slj[jcol + nj * 16];
        const unsigned short* rkrow = Rk + (size_t)jb * B_SZ;
#pragma unroll
        for (int mi = 0; mi < 4; ++mi) {
            const int i0 = it + irow0 + mi * 16;
            ushort4 rk4 = *reinterpret_cast<const ushort4*>(&rkrow[i0 & (B_SZ - 1)]);
            const unsigned short rr[4] = {rk4.x, rk4.y, rk4.z, rk4.w};
#pragma unroll
            for (int reg = 0; reg < 4; ++reg) {
                const int i_g = i0 + reg;
                if (i_g != j_g) {
                    const float s = acc[mi][nj][reg] * INV_T;
                    const float dl = sli[irow0 + mi * 16 + reg] - lj;
                    const float msk = __expf(dl * dl * (-0.5f)) * KC;
                    const int x = mi * 4 + reg;
                    rw[x] += msk;
                    rp[x] = fmaf(msk, s, rp[x]);
                    ru[x] = fmaf(__expf(s - INV_T), 2.0f * (float)rr[reg], ru[x]);
                }
            }
        }
    }

#pragma unroll
    for (int mi = 0; mi < 4; ++mi) {
#pragma unroll
        for (int reg = 0; reg < 4; ++reg) {
            const int x = mi * 4 + reg;
            float a = rw[x], b = rp[x], c = ru[x];
#pragma unroll
            for (int off = 8; off >= 1; off >>= 1) {
                a += __shfl_xor(a, off, 16);
                b += __shfl_xor(b, off, 16);
                c += __shfl_xor(c, off, 16);
            }
            if (lr == 0) {
                const int row = it + irow0 + mi * 16 + reg;
                atomicAdd(&Wacc[row], a);
                atomicAdd(&PSacc[row], b);
                atomicAdd(&Uacc[row], c);
            }
        }
    }
}

// ---------------- Kernel 3: final reduce ----------------
__global__ __launch_bounds__(256) void finish_kernel(const float* __restrict__ Uacc,
                                                     const float* __restrict__ Wacc,
                                                     const float* __restrict__ PSacc,
                                                     float* __restrict__ out) {
    __shared__ float red[4];
    const int t = threadIdx.x;
    float sum = 0.f;
    for (int r2 = t; r2 < N_SZ; r2 += 256)
        sum += PSacc[r2] / Wacc[r2] - INV_T - logf(Uacc[r2]);
#pragma unroll
    for (int off = 32; off >= 1; off >>= 1) sum += __shfl_xor(sum, off, 64);
    if ((t & 63) == 0) red[t >> 6] = sum;
    __syncthreads();
    if (t == 0) {
        float tot = red[0] + red[1] + red[2] + red[3];
        out[0] = -tot / (float)N_SZ;
    }
}

extern "C" void kernel_launch(void* const* d_in, const int* in_sizes, int n_in,
                              void* d_out, int out_size, void* d_ws, size_t ws_size,
                              hipStream_t stream) {
    const float* feats = (const float*)d_in[0];
    const float* labels = (const float*)d_in[1];
    float* out = (float*)d_out;

    char* ws = (char*)d_ws;
    unsigned short* Rk = (unsigned short*)ws;
    const size_t rk_bytes = (size_t)B_SZ * B_SZ * sizeof(unsigned short);  // 8 MB
    float* Uacc = (float*)(ws + rk_bytes);
    float* Wacc = Uacc + N_SZ;
    float* PSacc = Wacc + N_SZ;
    float* sorted = PSacc + N_SZ;
    unsigned short* lo = (unsigned short*)(sorted + B_SZ);
    unsigned short* hi = lo + B_SZ;
    __bf16* Hp = (__bf16*)(hi + B_SZ);

    hipMemsetAsync(Uacc, 0, 3 * N_SZ * sizeof(float), stream);
    conv_kernel<<<dim3(N_SZ), dim3(256), 0, stream>>>(feats, Hp);
    sort_kernel<<<dim3(8), dim3(256), 0, stream>>>(labels, sorted, lo, hi);
    rank_kernel<<<dim3(B_SZ), dim3(256), 0, stream>>>(labels, sorted, lo, hi, Rk);
    main_kernel<<<dim3(32, 32), dim3(256), 0, stream>>>(Hp, labels, Rk, Uacc, Wacc, PSacc);
    finish_kernel<<<dim3(1), dim3(256), 0, stream>>>(Uacc, Wacc, PSacc, out);
}